// Round 4
// baseline (284.867 us; speedup 1.0000x reference)
//
#include <hip/hip_runtime.h>

// Varifold loss, round 4: 4 i-rows per thread (i-panel = 1024) to amortize
// scalar j-loads 4x and give 4 independent acc chains. Symmetry at panel
// granularity: blocks (TI, tj) with tj >= 4*TI; in-band square weight 1
// (both orders computed), off-band weight 2.
//
// Per-face record (2 x float4):
//   rec0 = {Cx, Cy, Cz, cq = -gamma*log2e*|C|^2}
//   rec1 = {mx, my, mz, 0}   with m = Nn * sqrt(L)
// Pair term: exp2(cq_i + cq_j + 2*gamma*log2e*<Ci,Cj>) * <m_i,m_j>^2

#define NVERT 5023
#define NFACE 9976
#define BATCH 4
#define HALF  10240                 // pred slots padded to 40 tiles of 256
#define NTP   (2 * HALF)            // 20480 padded faces per batch
#define JTILES 80                   // NTP / 256
#define IPANELS 20                  // NTP / 1024
#define NBLK 840                    // sum_{TI<20} (80 - 4*TI)

constexpr float GAMMA = 1.0f / (0.03f * 0.03f);
constexpr float LOG2E = 1.4426950408889634f;
constexpr float EPSV  = 1e-12f;

__global__ __launch_bounds__(256)
void face_quant_kernel(const float* __restrict__ pred,
                       const float* __restrict__ targ,
                       const int*   __restrict__ faces,
                       float4*      __restrict__ fd,
                       float*       __restrict__ out) {
    int idx = blockIdx.x * 256 + threadIdx.x;
    if (idx == 0) out[0] = 0.0f;            // runs before pair_sum on stream
    const int total = BATCH * NTP;
    if (idx >= total) return;

    int b     = idx / NTP;
    int s     = idx - b * NTP;
    int which = (s >= HALF) ? 1 : 0;        // 0 = pred(+), 1 = targ(-)
    int f     = s - which * HALF;

    float4 r0 = make_float4(0.f, 0.f, 0.f, 0.f);
    float4 r1 = make_float4(0.f, 0.f, 0.f, 0.f);

    if (f < NFACE) {
        const float* V = (which ? targ : pred) + (size_t)b * NVERT * 3;
        int i0 = faces[f * 3 + 0];
        int i1 = faces[f * 3 + 1];
        int i2 = faces[f * 3 + 2];

        float v0x = V[i0*3+0], v0y = V[i0*3+1], v0z = V[i0*3+2];
        float v1x = V[i1*3+0], v1y = V[i1*3+1], v1z = V[i1*3+2];
        float v2x = V[i2*3+0], v2y = V[i2*3+1], v2z = V[i2*3+2];

        const float third = 1.0f / 3.0f;
        float cx = (v0x + v1x + v2x) * third;
        float cy = (v0y + v1y + v2y) * third;
        float cz = (v0z + v1z + v2z) * third;

        float e1x = v1x - v0x, e1y = v1y - v0y, e1z = v1z - v0z;
        float e2x = v2x - v0x, e2y = v2y - v0y, e2z = v2z - v0z;

        float nx = 0.5f * (e1y * e2z - e1z * e2y);
        float ny = 0.5f * (e1z * e2x - e1x * e2z);
        float nz = 0.5f * (e1x * e2y - e1y * e2x);

        float L   = sqrtf(nx*nx + ny*ny + nz*nz);
        float inv = 1.0f / fmaxf(L, EPSV);
        float sc  = inv * sqrtf(L);          // m = N/L * sqrt(L)

        float cq  = -GAMMA * LOG2E * (cx*cx + cy*cy + cz*cz);
        r0 = make_float4(cx, cy, cz, cq);
        r1 = make_float4(nx * sc, ny * sc, nz * sc, 0.f);
    }
    fd[(size_t)idx * 2 + 0] = r0;
    fd[(size_t)idx * 2 + 1] = r1;
}

__global__ __launch_bounds__(256)
void pair_sum_kernel(const float4* __restrict__ fd,
                     float*        __restrict__ out) {
    const int b  = blockIdx.z;

    // decode (TI, tj): TI in [0,20), tj in [4*TI, 80)
    int TI = 0, rem = blockIdx.x;
    while (rem >= JTILES - 4 * TI) { rem -= JTILES - 4 * TI; ++TI; }
    int tj = 4 * TI + rem;

    const float4* base = fd + (size_t)b * NTP * 2;

    const float TG = 2.0f * GAMMA * LOG2E;

    // 4 i-rows per thread: i = TI*1024 + r*256 + tid
    float Ax[4], Ay[4], Az[4], cq[4], mx[4], my[4], mz[4];
    float acc[4];
    #pragma unroll
    for (int r = 0; r < 4; ++r) {
        int i = TI * 1024 + r * 256 + threadIdx.x;
        float4 ci = base[(size_t)i * 2 + 0];
        float4 mi = base[(size_t)i * 2 + 1];
        Ax[r] = TG * ci.x;  Ay[r] = TG * ci.y;  Az[r] = TG * ci.z;
        cq[r] = ci.w;
        mx[r] = mi.x;  my[r] = mi.y;  mz[r] = mi.z;
        acc[r] = 0.0f;
    }

    const int j0 = tj * 256;
    #pragma unroll 2
    for (int jj = 0; jj < 256; ++jj) {
        int j = j0 + jj;                      // wave-uniform -> s_load
        float4 cj = base[(size_t)j * 2 + 0];
        float4 mj = base[(size_t)j * 2 + 1];

        #pragma unroll
        for (int r = 0; r < 4; ++r) {
            float t = cq[r] + cj.w;
            t = fmaf(Ax[r], cj.x, t);
            t = fmaf(Ay[r], cj.y, t);
            t = fmaf(Az[r], cj.z, t);

            float d = mx[r] * mj.x;
            d = fmaf(my[r], mj.y, d);
            d = fmaf(mz[r], mj.z, d);

            float e = __builtin_amdgcn_exp2f(t);
            acc[r] = fmaf(e, d * d, acc[r]);
        }
    }

    // uniform post-scale: signs, band weight, 1/B
    float si  = (TI < IPANELS / 2) ? 1.0f : -1.0f;
    float sj  = (tj < JTILES / 2) ? 1.0f : -1.0f;
    float wgt = (tj >= 4 * TI + 4) ? 2.0f : 1.0f;
    float fac = si * sj * wgt * (1.0f / BATCH);
    float accv = (acc[0] + acc[1] + acc[2] + acc[3]) * fac;

    #pragma unroll
    for (int off = 32; off > 0; off >>= 1)
        accv += __shfl_down(accv, off, 64);

    __shared__ float wsum[4];
    int lane = threadIdx.x & 63;
    int wv   = threadIdx.x >> 6;
    if (lane == 0) wsum[wv] = accv;
    __syncthreads();
    if (threadIdx.x == 0) {
        atomicAdd(out, wsum[0] + wsum[1] + wsum[2] + wsum[3]);
    }
}

extern "C" void kernel_launch(void* const* d_in, const int* in_sizes, int n_in,
                              void* d_out, int out_size, void* d_ws, size_t ws_size,
                              hipStream_t stream) {
    const float* pred  = (const float*)d_in[0];
    const float* targ  = (const float*)d_in[1];
    const int*   faces = (const int*)d_in[2];
    float*       out   = (float*)d_out;
    float4*      fd    = (float4*)d_ws;      // BATCH*NTP*2 float4 = 2.62 MB

    const int totalSlots = BATCH * NTP;
    face_quant_kernel<<<(totalSlots + 255) / 256, 256, 0, stream>>>(
        pred, targ, faces, fd, out);

    dim3 grid(NBLK, 1, BATCH);
    pair_sum_kernel<<<grid, 256, 0, stream>>>(fd, out);
}